// Round 8
// baseline (133.680 us; speedup 1.0000x reference)
//
#include <hip/hip_runtime.h>
#include <math.h>

// FactorizationMachine v6b = v5 + non-temporal embedding loads (compile fix:
// __builtin_nontemporal_load needs an ext_vector pointer, not HIP_vector_type).
// Theory: the 52 MB single-use embedding gather stream thrashes the 4 MiB/XCD
// L2s, evicting the hot 4 MB weights table (gathered 819K times) -> extra HBM
// re-fetches (~16 MB of the 86 MB FETCH). 'nt' on embedding loads keeps L2 for
// weights/feats; embedding dup-accesses (32%) still hit the memory-side L3.

typedef float fvec4 __attribute__((ext_vector_type(4)));

__global__ __launch_bounds__(256) void seg_starts(
    const int* __restrict__ index, int* __restrict__ starts, int nnz, int batch)
{
    const int i = blockIdx.x * blockDim.x + threadIdx.x;
    if (i >= nnz) return;
    const int cur  = index[i];
    const int prev = (i == 0) ? -1 : index[i - 1];
    for (int b = prev + 1; b <= cur; ++b) starts[b] = i;
    if (i == nnz - 1) {
        for (int b = cur + 1; b <= batch; ++b) starts[b] = nnz;
    }
}

__global__ __launch_bounds__(256) void fm6(
    const int* __restrict__ feats,
    const float* __restrict__ values,
    const float* __restrict__ bias,
    const float* __restrict__ weights,
    const float* __restrict__ embedding,
    const int* __restrict__ starts,
    float* __restrict__ out,
    int batch)
{
    __shared__ int2 buf[4][128];           // {feat, bits(value)}, 4 KB/block

    const int wslot = (int)(threadIdx.x >> 6);
    const int wave  = blockIdx.x * 4 + wslot;
    const int lane  = (int)(threadIdx.x & 63);
    if (wave >= batch) return;
    const int b = wave;

    const int start = starts[b];
    const int end   = starts[b + 1];

    const int q = lane & 3;                // float4 quad of columns (k = 4q..4q+3)
    const int j = lane >> 2;               // item slot within a 16-item step

    fvec4 t1 = (fvec4)(0.0f);
    fvec4 t2 = (fvec4)(0.0f);
    float ws = 0.0f;

    for (int base = start; base < end; base += 128) {
        const int cnt = min(end - base, 128);

        // ---- Phase A: coalesced preload + first-order term ----
        if (lane < cnt) {
            const int   f = feats[base + lane];
            const float v = values[base + lane];
            buf[wslot][lane] = make_int2(f, __float_as_int(v));
            ws += weights[f] * v;          // independent gather, off critical path
        }
        const int i2 = lane + 64;
        if (i2 < cnt) {
            const int   f = feats[base + i2];
            const float v = values[base + i2];
            buf[wslot][i2] = make_int2(f, __float_as_int(v));
            ws += weights[f] * v;
        }
        // wave-local LDS produce->consume ordering (no cross-wave sync needed)
        asm volatile("s_waitcnt lgkmcnt(0)" ::: "memory");

        // ---- Phase B: float4 gathers, 4-deep, non-temporal ----
        for (int t0 = 0; t0 < cnt; t0 += 64) {
            int   f[4]; float v[4];
#pragma unroll
            for (int u = 0; u < 4; ++u) {
                const int item = t0 + 16 * u + j;      // 4-lane broadcast from LDS
                const int2 fv = buf[wslot][item < cnt ? item : 0];
                f[u] = fv.x;
                v[u] = (item < cnt) ? __int_as_float(fv.y) : 0.0f;  // branchless tail
            }
            fvec4 e[4];
#pragma unroll
            for (int u = 0; u < 4; ++u)
                e[u] = __builtin_nontemporal_load(
                           reinterpret_cast<const fvec4*>(embedding + (size_t)f[u] * 16) + q);
#pragma unroll
            for (int u = 0; u < 4; ++u) {
                const fvec4 ev = e[u] * v[u];
                t1 += ev;
                t2 += ev * ev;
            }
        }
    }

    // j-reduce t1/t2 across the 16 item-slots (xor bits 2..5)
#pragma unroll
    for (int off = 4; off <= 32; off <<= 1) {
        t1.x += __shfl_xor(t1.x, off, 64); t1.y += __shfl_xor(t1.y, off, 64);
        t1.z += __shfl_xor(t1.z, off, 64); t1.w += __shfl_xor(t1.w, off, 64);
        t2.x += __shfl_xor(t2.x, off, 64); t2.y += __shfl_xor(t2.y, off, 64);
        t2.z += __shfl_xor(t2.z, off, 64); t2.w += __shfl_xor(t2.w, off, 64);
    }

    // full-wave reduce of first-order partials (each item counted once)
    ws += __shfl_xor(ws, 1, 64);  ws += __shfl_xor(ws, 2, 64);
    ws += __shfl_xor(ws, 4, 64);  ws += __shfl_xor(ws, 8, 64);
    ws += __shfl_xor(ws, 16, 64); ws += __shfl_xor(ws, 32, 64);

    // second order: in-lane fold of this lane's 4 columns, then q-reduce
    float sec = (t1.x * t1.x - t2.x) + (t1.y * t1.y - t2.y)
              + (t1.z * t1.z - t2.z) + (t1.w * t1.w - t2.w);
    sec += __shfl_xor(sec, 1, 64);
    sec += __shfl_xor(sec, 2, 64);

    if (lane == 0) {
        const float x = ws + bias[0] + 0.5f * sec;
        out[b] = 1.0f / (1.0f + expf(-x));
    }
}

extern "C" void kernel_launch(void* const* d_in, const int* in_sizes, int n_in,
                              void* d_out, int out_size, void* d_ws, size_t ws_size,
                              hipStream_t stream) {
    // setup_inputs order: batch_size, index, feats, values, bias, weights, embedding
    const int*   index     = (const int*)d_in[1];
    const int*   feats     = (const int*)d_in[2];
    const float* values    = (const float*)d_in[3];
    const float* bias      = (const float*)d_in[4];
    const float* weights   = (const float*)d_in[5];
    const float* embedding = (const float*)d_in[6];
    float* out = (float*)d_out;

    const int nnz   = in_sizes[1];
    const int batch = out_size;               // output is (1, BATCH)

    int* starts = (int*)d_ws;                 // batch+1 ints, ws is plenty
    seg_starts<<<(nnz + 255) / 256, 256, 0, stream>>>(index, starts, nnz, batch);

    const int fm_blocks = (batch + 3) / 4;    // 4 waves (samples) per block
    fm6<<<fm_blocks, 256, 0, stream>>>(feats, values, bias, weights,
                                       embedding, starts, out, batch);
}

// Round 9
// 126.813 us; speedup vs baseline: 1.0541x; 1.0541x over previous
//
#include <hip/hip_runtime.h>
#include <math.h>

// FactorizationMachine v5 (final revert — nt-load experiment in v6b regressed:
// 'nt' bypasses the memory-side L3 that was serving ~32% duplicate embedding
// rows). Evidence trail: v4->v5 MLP-quadrupling neutral; v5->v6b cache-policy
// regression; effective random-gather rate ~3.3 TB/s vs 6.5 TB/s stream =
// the 128B-line random service ceiling. This kernel is the measured optimum.
// seg_starts: index sorted -> starts[] (one pass, no binary search).
// fm5: one wave per sample. lane = (j<<2)|q : j in [0,16) item slot,
//   q in [0,4) float4 column-quad. Phase A: coalesced (f,v) preload -> LDS +
//   first-order fold. Phase B: float4 gathers, 4-deep, 64 lines in flight.

__global__ __launch_bounds__(256) void seg_starts(
    const int* __restrict__ index, int* __restrict__ starts, int nnz, int batch)
{
    const int i = blockIdx.x * blockDim.x + threadIdx.x;
    if (i >= nnz) return;
    const int cur  = index[i];
    const int prev = (i == 0) ? -1 : index[i - 1];
    for (int b = prev + 1; b <= cur; ++b) starts[b] = i;
    if (i == nnz - 1) {
        for (int b = cur + 1; b <= batch; ++b) starts[b] = nnz;
    }
}

__global__ __launch_bounds__(256) void fm5(
    const int* __restrict__ feats,
    const float* __restrict__ values,
    const float* __restrict__ bias,
    const float* __restrict__ weights,
    const float* __restrict__ embedding,
    const int* __restrict__ starts,
    float* __restrict__ out,
    int batch)
{
    __shared__ int2 buf[4][128];           // {feat, bits(value)}, 4 KB/block

    const int wslot = (int)(threadIdx.x >> 6);
    const int wave  = blockIdx.x * 4 + wslot;
    const int lane  = (int)(threadIdx.x & 63);
    if (wave >= batch) return;
    const int b = wave;

    const int start = starts[b];
    const int end   = starts[b + 1];

    const int q = lane & 3;                // float4 quad of columns (k = 4q..4q+3)
    const int j = lane >> 2;               // item slot within a 16-item step

    float4 t1 = make_float4(0.f, 0.f, 0.f, 0.f);
    float4 t2 = make_float4(0.f, 0.f, 0.f, 0.f);
    float  ws = 0.0f;

    for (int base = start; base < end; base += 128) {
        const int cnt = min(end - base, 128);

        // ---- Phase A: coalesced preload + first-order term ----
        if (lane < cnt) {
            const int   f = feats[base + lane];
            const float v = values[base + lane];
            buf[wslot][lane] = make_int2(f, __float_as_int(v));
            ws += weights[f] * v;          // independent gather, off critical path
        }
        const int i2 = lane + 64;
        if (i2 < cnt) {
            const int   f = feats[base + i2];
            const float v = values[base + i2];
            buf[wslot][i2] = make_int2(f, __float_as_int(v));
            ws += weights[f] * v;
        }
        // wave-local LDS produce->consume ordering (no cross-wave sync needed)
        asm volatile("s_waitcnt lgkmcnt(0)" ::: "memory");

        // ---- Phase B: float4 gathers, 4-deep (64 lines in flight / wave) ----
        for (int t0 = 0; t0 < cnt; t0 += 64) {
            int   f[4]; float v[4];
#pragma unroll
            for (int u = 0; u < 4; ++u) {
                const int item = t0 + 16 * u + j;      // 4-lane broadcast from LDS
                const int2 fv = buf[wslot][item < cnt ? item : 0];
                f[u] = fv.x;
                v[u] = (item < cnt) ? __int_as_float(fv.y) : 0.0f;  // branchless tail
            }
            float4 e[4];
#pragma unroll
            for (int u = 0; u < 4; ++u)
                e[u] = *(const float4*)(embedding + (size_t)f[u] * 16 + 4 * q);
#pragma unroll
            for (int u = 0; u < 4; ++u) {
                const float4 eu = e[u];
                float ev;
                ev = eu.x * v[u]; t1.x += ev; t2.x += ev * ev;
                ev = eu.y * v[u]; t1.y += ev; t2.y += ev * ev;
                ev = eu.z * v[u]; t1.z += ev; t2.z += ev * ev;
                ev = eu.w * v[u]; t1.w += ev; t2.w += ev * ev;
            }
        }
    }

    // j-reduce t1/t2 across the 16 item-slots (xor bits 2..5)
#pragma unroll
    for (int off = 4; off <= 32; off <<= 1) {
        t1.x += __shfl_xor(t1.x, off, 64); t1.y += __shfl_xor(t1.y, off, 64);
        t1.z += __shfl_xor(t1.z, off, 64); t1.w += __shfl_xor(t1.w, off, 64);
        t2.x += __shfl_xor(t2.x, off, 64); t2.y += __shfl_xor(t2.y, off, 64);
        t2.z += __shfl_xor(t2.z, off, 64); t2.w += __shfl_xor(t2.w, off, 64);
    }

    // full-wave reduce of first-order partials (each item counted once)
    ws += __shfl_xor(ws, 1, 64);  ws += __shfl_xor(ws, 2, 64);
    ws += __shfl_xor(ws, 4, 64);  ws += __shfl_xor(ws, 8, 64);
    ws += __shfl_xor(ws, 16, 64); ws += __shfl_xor(ws, 32, 64);

    // second order: in-lane fold of this lane's 4 columns, then q-reduce
    float sec = (t1.x * t1.x - t2.x) + (t1.y * t1.y - t2.y)
              + (t1.z * t1.z - t2.z) + (t1.w * t1.w - t2.w);
    sec += __shfl_xor(sec, 1, 64);
    sec += __shfl_xor(sec, 2, 64);

    if (lane == 0) {
        const float x = ws + bias[0] + 0.5f * sec;
        out[b] = 1.0f / (1.0f + expf(-x));
    }
}

extern "C" void kernel_launch(void* const* d_in, const int* in_sizes, int n_in,
                              void* d_out, int out_size, void* d_ws, size_t ws_size,
                              hipStream_t stream) {
    // setup_inputs order: batch_size, index, feats, values, bias, weights, embedding
    const int*   index     = (const int*)d_in[1];
    const int*   feats     = (const int*)d_in[2];
    const float* values    = (const float*)d_in[3];
    const float* bias      = (const float*)d_in[4];
    const float* weights   = (const float*)d_in[5];
    const float* embedding = (const float*)d_in[6];
    float* out = (float*)d_out;

    const int nnz   = in_sizes[1];
    const int batch = out_size;               // output is (1, BATCH)

    int* starts = (int*)d_ws;                 // batch+1 ints, ws is plenty
    seg_starts<<<(nnz + 255) / 256, 256, 0, stream>>>(index, starts, nnz, batch);

    const int fm_blocks = (batch + 3) / 4;    // 4 waves (samples) per block
    fm5<<<fm_blocks, 256, 0, stream>>>(feats, values, bias, weights,
                                       embedding, starts, out, batch);
}